// Round 11
// baseline (175.236 us; speedup 1.0000x reference)
//
#include <hip/hip_runtime.h>
#include <math.h>

#define NN 200000
#define DD 64
#define BB 4096
#define KK 128
#define WW 20
#define HH 128
#define TPB 512
#define RPB 4        // targets per block
#define TSTRIDE 260  // tile row stride: 260 mod 32 = 4 -> r-rows staggered 4 banks

__device__ __forceinline__ float fast_rcp(float x) { return __builtin_amdgcn_rcpf(x); }
__device__ __forceinline__ float fast_rsq(float x) { return __builtin_amdgcn_rsqf(x); }
__device__ __forceinline__ float readlane_f(float v, int l) {
    return __builtin_bit_cast(float, __builtin_amdgcn_readlane(__builtin_bit_cast(int, v), l));
}

// ---------------- K0: per-NODE encoding precompute ----------------
// R6-R10 all plateaued at ~42us = VALU-issue bound: each of 524K neighbor
// slots re-derived its node encoding TWICE (phase1 + phase3) = 67M cos-feature
// evals, but there are only 200K distinct nodes. Precompute once per node:
//   fn[n][64]  : L2-normalized encoding (51.2 MB, L3-resident)
//   snt[n]     : {sdn = fn . att_w[64:], ts = 1/(2 ln(e+dt))}
// Wave per node (lane = dim): 1 cos/lane, dual shuffle-reduce, coalesced
// 256B row store. 50000 blocks x 256 thr.
__global__ __launch_bounds__(256) void k0_nodes(
    const float* __restrict__ adj_time, const float* __restrict__ gc,
    const float* __restrict__ cur_time,
    const float* __restrict__ t2v_w, const float* __restrict__ t2v_b,
    const float* __restrict__ node_w, const float* __restrict__ node_b,
    const float* __restrict__ att_w,
    float* __restrict__ fn, float2* __restrict__ snt)
{
    const int tid  = threadIdx.x;
    const int lane = tid & 63;
    const int node = blockIdx.x * 4 + (tid >> 6);   // 200000/4 = 50000 exact

    const float t  = cur_time[0];
    const float at = adj_time[node];                // wave-uniform -> s_load
    const float g  = gc[node];
    const float dt = fabsf(t - at);

    float ph = fmaf(t2v_w[lane], dt, t2v_b[lane]);
    float tv = (lane == 0) ? ph : __cosf(ph);
    float f  = fmaxf(tv + fmaf(g, node_w[lane], node_b[lane]), 0.f);

    float s2 = f * f;
    float sd = f * att_w[64 + lane];
#pragma unroll
    for (int off = 32; off; off >>= 1) {
        s2 += __shfl_xor(s2, off, 64);
        sd += __shfl_xor(sd, off, 64);
    }
    float invn = fast_rsq(fmaxf(s2, 1e-24f));
    fn[(size_t)node * 64 + lane] = f * invn;        // coalesced 256B row
    if (lane == 0) {
        float ts = fast_rcp(2.0f * __logf(2.71828182845904523536f + (t - at)));
        snt[node] = make_float2(sd * invn, ts);
    }
}

// ---------------- K1: fused aggregation + GEMM (NO cos anywhere) ----------------
// TPB=512, RPB=4, grid 1024 (4 blocks/CU). vs R10:
//   - phase 1 deleted: wk = leaky(ts + stL + sdn + ab)*mask  (fn already
//     normalized, so no invn factor on the weight).
//   - phase 3: per j, {idx, wk} via readlane (SGPR base addressing), then one
//     coalesced global_load_dword of fn[idx][lane] (256B/wave, L3-hot) + FMA.
//   - target encoding = fn row gather + one shuffle reduce.
//   - hist + barrier-free GEMM identical to R10.
__global__ __launch_bounds__(512, 8) void fused(
    const float* __restrict__ cur_time, const float* __restrict__ neigh_mask,
    const float* __restrict__ hist_feat, const float* __restrict__ hist_time,
    const float* __restrict__ att_w, const float* __restrict__ att_b,
    const float* __restrict__ weight,
    const int* __restrict__ targets, const int* __restrict__ neigh_idx,
    const float* __restrict__ fn, const float2* __restrict__ snt,
    float* __restrict__ out)
{
    const int b0   = blockIdx.x * RPB;
    const int tid  = threadIdx.x;
    const int lane = tid & 63;
    const int wv   = tid >> 6;          // wave id 0..7
    const int r_   = tid >> 7;          // target row 0..3 (wave-uniform)
    const int d_   = tid & 127;

    __shared__ float hws[RPB][WW];
    __shared__ float stL[RPB];
    __shared__ float tile[RPB * TSTRIDE];
    __shared__ float aggp[8][64];

    const float t = cur_time[0];

    // ---- gathers: slot = tid; 3 scalars per slot from L2-hot tables ----
    int    idx = neigh_idx[b0 * KK + tid];
    float  m_k = neigh_mask[b0 * KK + tid];
    float2 s   = snt[idx];              // {sdn, ts}

    if (tid < RPB * WW) {
        int r = tid / WW, w = tid - r * WW;
        hws[r][w] = fast_rcp(2.0f * (1.0f + (t - hist_time[(b0 + r) * WW + w])));
    }
    if (wv < RPB) {                     // target: gather fn row + reduce att-dot
        int   tg  = targets[b0 + wv];
        float tfn = fn[(size_t)tg * 64 + lane];
        float sdt = tfn * att_w[lane];
#pragma unroll
        for (int off = 32; off; off >>= 1) sdt += __shfl_xor(sdt, off, 64);
        if (lane == 0) stL[wv] = sdt;
        tile[wv * TSTRIDE + 128 + lane] = tfn;
    }
    __syncthreads();   // A: hws + stL ready

    // ---- attention weight (register; fn already normalized -> no invn) ----
    float wk;
    {
        float sc = s.y + stL[r_] + s.x + att_b[0];
        sc = (sc > 0.f) ? sc : 0.01f * sc;          // leaky_relu(0.01)
        wk = sc * m_k;
    }

    // ---- history aggregation into tile cols 0-127 ----
    {
        const float* hf = hist_feat + (size_t)(b0 + r_) * WW * 128 + d_;
        float hs = 0.f;
#pragma unroll
        for (int w = 0; w < WW; ++w) hs = fmaf(hws[r_][w], hf[w * 128], hs);
        tile[r_ * TSTRIDE + d_] = hs;
    }

    // ---- phase 3: lane = dim; per j: readlane {idx,wk} + fn row load + FMA ----
    {
        float acc = 0.f;
#pragma unroll
        for (int j = 0; j < 64; ++j) {
            int   ij  = __builtin_amdgcn_readlane(idx, j);   // SGPR
            float wkj = readlane_f(wk, j);
            float fv  = fn[(size_t)ij * 64 + lane];          // saddr + lane*4, 256B coalesced
            acc = fmaf(wkj, fv, acc);
        }
        aggp[wv][lane] = acc;
    }
    __syncthreads();   // D

    if (!(wv & 1))
        tile[(wv >> 1) * TSTRIDE + 192 + lane] = aggp[wv][lane] + aggp[wv | 1][lane];
    __syncthreads();   // E: tile complete

    // ---- GEMM (barrier-free): thread = (h = wv*16 + lane>>2, r = lane&3) ----
    {
        const int h = wv * 16 + (lane >> 2);
        const int r = lane & 3;
        const float4* wrow = (const float4*)(weight + (size_t)h * 256);
        const float*  tb   = tile + r * TSTRIDE;
        float acc = 0.f;
#pragma unroll 8
        for (int j = 0; j < 64; ++j) {
            float4 w4 = wrow[j];                       // global, quad-merged, L2-hot
            float4 f4 = *(const float4*)(tb + 4 * j);  // LDS b128, conflict-free
            acc += w4.x * f4.x + w4.y * f4.y + w4.z * f4.z + w4.w * f4.w;
        }
        out[(size_t)(b0 + r) * 128 + h] = fmaxf(acc, 0.f);
    }
}

extern "C" void kernel_launch(void* const* d_in, const int* in_sizes, int n_in,
                              void* d_out, int out_size, void* d_ws, size_t ws_size,
                              hipStream_t stream) {
    const float* adj_time  = (const float*)d_in[0];
    const float* gc        = (const float*)d_in[1];
    const float* cur_time  = (const float*)d_in[2];
    const float* neigh_mask= (const float*)d_in[3];
    const float* hist_feat = (const float*)d_in[4];
    const float* hist_time = (const float*)d_in[5];
    const float* t2v_w     = (const float*)d_in[6];
    const float* t2v_b     = (const float*)d_in[7];
    const float* node_w    = (const float*)d_in[8];
    const float* node_b    = (const float*)d_in[9];
    const float* att_w     = (const float*)d_in[10];
    const float* att_b     = (const float*)d_in[11];
    const float* weight    = (const float*)d_in[12];
    const int*   targets   = (const int*)d_in[13];
    const int*   neigh_idx = (const int*)d_in[14];

    float* out = (float*)d_out;

    // workspace layout: fn[NN][64] fp32 (51.2 MB) | snt[NN] float2 (1.6 MB)
    float*  fn  = (float*)d_ws;
    float2* snt = (float2*)((char*)d_ws + (size_t)NN * 64 * sizeof(float));

    k0_nodes<<<NN / 4, 256, 0, stream>>>(adj_time, gc, cur_time,
                                         t2v_w, t2v_b, node_w, node_b, att_w,
                                         fn, snt);

    fused<<<BB / RPB, TPB, 0, stream>>>(cur_time, neigh_mask,
                                        hist_feat, hist_time,
                                        att_w, att_b, weight,
                                        targets, neigh_idx, fn, snt, out);
}